// Round 10
// baseline (769.336 us; speedup 1.0000x reference)
//
#include <hip/hip_runtime.h>
#include <hip/hip_bf16.h>

#define NB 16
#define N2V 618
#define N3V 2466
#define FEAT 963
#define HID 192
#define IN_DIM 1163
#define KPAD2 1216         // 1163 padded to 38*32
#define ETILES 38
#define EHALF 19
#define MTOT (NB * N3V)    // 39456
#define M2   (NB * N2V)    // 9888

typedef __attribute__((ext_vector_type(8))) short bf16x8;
typedef __attribute__((ext_vector_type(4))) float f32x4;

__device__ __forceinline__ float bf2f(ushort u) {
    return __uint_as_float(((unsigned)u) << 16);
}
__device__ __forceinline__ ushort f2bf(float f) {   // round-to-nearest-even
    unsigned u = __float_as_uint(f);
    return (ushort)((u + 0x7FFFu + ((u >> 16) & 1u)) >> 16);
}
// bijective XCD-chunk swizzle (m204)
__device__ __forceinline__ int xcd_swz(int bid, int G) {
    int q = G >> 3, r = G & 7;
    int xcd = bid & 7, slot = bid >> 3;
    return (xcd < r) ? xcd * (q + 1) + slot : r * (q + 1) + (xcd - r) * q + slot;
}

// ---------------------------------------------------------------------------
// q,k,v projections: mv grade-1 only -> rows 1..3 of W
// ---------------------------------------------------------------------------
__global__ void qkv_kernel(const float* __restrict__ x2,
                           const float* __restrict__ Wq, const float* __restrict__ bq,
                           const float* __restrict__ Wk, const float* __restrict__ bk,
                           const float* __restrict__ Wv, const float* __restrict__ bv,
                           float* __restrict__ q, float* __restrict__ k, float* __restrict__ v)
{
    int idx = blockIdx.x * 256 + threadIdx.x;
    if (idx >= M2) return;
    float c0 = x2[idx * 3 + 0], c1 = x2[idx * 3 + 1], c2 = x2[idx * 3 + 2];
#pragma unroll
    for (int d = 0; d < 8; ++d) {
        q[idx * 8 + d] = bq[d] + c0 * Wq[8 + d] + c1 * Wq[16 + d] + c2 * Wq[24 + d];
        k[idx * 8 + d] = bk[d] + c0 * Wk[8 + d] + c1 * Wk[16 + d] + c2 * Wk[24 + d];
        v[idx * 8 + d] = bv[d] + c0 * Wv[8 + d] + c1 * Wv[16 + d] + c2 * Wv[24 + d];
    }
}

// ---------------------------------------------------------------------------
// attention: block = (batch, 64 queries); K,V staged in LDS (39.6KB);
// 4 lanes per query, online softmax, shfl merge across the 4 sub-lanes.
// ---------------------------------------------------------------------------
__global__ __launch_bounds__(256) void attn_kernel2(const float* __restrict__ q,
                                                    const float* __restrict__ k,
                                                    const float* __restrict__ v,
                                                    float* __restrict__ att)
{
    __shared__ float4 kv[N2V * 4];            // K: [0,2*N2V), V: [2*N2V,4*N2V)
    int b = blockIdx.x, qb = blockIdx.y;
    const float4* k4 = (const float4*)(k + (size_t)b * N2V * 8);
    const float4* v4 = (const float4*)(v + (size_t)b * N2V * 8);
    for (int i = threadIdx.x; i < N2V * 2; i += 256) {
        kv[i] = k4[i];
        kv[N2V * 2 + i] = v4[i];
    }
    __syncthreads();

    int ql = threadIdx.x >> 2, sub = threadIdx.x & 3;
    int qi = qb * 64 + ql;
    bool valid = qi < N2V;
    float qv[8];
#pragma unroll
    for (int d = 0; d < 8; ++d) qv[d] = 0.f;
    if (valid) {
#pragma unroll
        for (int d = 0; d < 8; ++d) qv[d] = q[((size_t)b * N2V + qi) * 8 + d];
    }

    const float scale = 0.35355339059327373f;
    float m = -3.0e38f, lsum = 0.f, acc[8];
#pragma unroll
    for (int d = 0; d < 8; ++d) acc[d] = 0.f;

    for (int kk = sub; kk < N2V; kk += 4) {
        float4 k0 = kv[kk * 2], k1 = kv[kk * 2 + 1];
        float s = qv[0] * k0.x + qv[1] * k0.y + qv[2] * k0.z + qv[3] * k0.w
                + qv[4] * k1.x + qv[5] * k1.y + qv[6] * k1.z + qv[7] * k1.w;
        s *= scale;
        float nm = fmaxf(m, s);
        float corr = __expf(m - nm);
        float p = __expf(s - nm);
        lsum = lsum * corr + p;
        float4 v0 = kv[N2V * 2 + kk * 2], v1 = kv[N2V * 2 + kk * 2 + 1];
        acc[0] = acc[0] * corr + p * v0.x; acc[1] = acc[1] * corr + p * v0.y;
        acc[2] = acc[2] * corr + p * v0.z; acc[3] = acc[3] * corr + p * v0.w;
        acc[4] = acc[4] * corr + p * v1.x; acc[5] = acc[5] * corr + p * v1.y;
        acc[6] = acc[6] * corr + p * v1.z; acc[7] = acc[7] * corr + p * v1.w;
        m = nm;
    }
#pragma unroll
    for (int o = 1; o <= 2; o <<= 1) {
        float m2 = __shfl_xor(m, o);
        float l2 = __shfl_xor(lsum, o);
        float nm = fmaxf(m, m2);
        float c1 = __expf(m - nm), c2 = __expf(m2 - nm);
        lsum = lsum * c1 + l2 * c2;
#pragma unroll
        for (int d = 0; d < 8; ++d) {
            float a2 = __shfl_xor(acc[d], o);
            acc[d] = acc[d] * c1 + a2 * c2;
        }
        m = nm;
    }
    if (valid && sub == 0) {
#pragma unroll
        for (int d = 0; d < 8; ++d)
            att[((size_t)b * N2V + qi) * 8 + d] = acc[d] / lsum;
    }
}

// ---------------------------------------------------------------------------
// adjacency prep: <=6 (col,val) per row (sorted), plus entry-layer expansion
// through the unpool midpoints (adj@Up, <=12 gathers) and self parent pair.
// ---------------------------------------------------------------------------
__global__ void adj_prep(const float* __restrict__ adj, const int* __restrict__ unpool,
                         int* __restrict__ cols, float* __restrict__ vals,
                         int* __restrict__ eidx, float* __restrict__ ew,
                         int* __restrict__ sidx)
{
    int m = blockIdx.x;
    __shared__ int cnt;
    __shared__ int lc[8];
    __shared__ float lv[8];
    if (threadIdx.x == 0) cnt = 0;
    __syncthreads();
    for (int c = threadIdx.x; c < N3V; c += 256) {
        float a = adj[(size_t)m * N3V + c];
        if (a != 0.f) {
            int p = atomicAdd(&cnt, 1);
            if (p < 6) { lc[p] = c; lv[p] = a; }
        }
    }
    __syncthreads();
    if (threadIdx.x == 0) {
        int n = cnt < 6 ? cnt : 6;
        for (int i = 1; i < n; ++i) {
            int ci = lc[i]; float vi = lv[i]; int j = i - 1;
            while (j >= 0 && lc[j] > ci) { lc[j + 1] = lc[j]; lv[j + 1] = lv[j]; --j; }
            lc[j + 1] = ci; lv[j + 1] = vi;
        }
        int ne = 0;
        for (int i = 0; i < 6; ++i) {
            int c = (i < n) ? lc[i] : 0;
            float w = (i < n) ? lv[i] : 0.f;
            cols[m * 6 + i] = c;
            vals[m * 6 + i] = w;
            if (i < n) {
                if (c < N2V) { eidx[m * 12 + ne] = c; ew[m * 12 + ne] = w; ++ne; }
                else {
                    int jj = c - N2V;
                    eidx[m * 12 + ne] = unpool[2 * jj];     ew[m * 12 + ne] = 0.5f * w; ++ne;
                    eidx[m * 12 + ne] = unpool[2 * jj + 1]; ew[m * 12 + ne] = 0.5f * w; ++ne;
                }
            }
        }
        for (; ne < 12; ++ne) { eidx[m * 12 + ne] = 0; ew[m * 12 + ne] = 0.f; }
        if (m < N2V) { sidx[m * 2] = m; sidx[m * 2 + 1] = -1; }
        else {
            int j = m - N2V;
            sidx[m * 2] = unpool[2 * j];
            sidx[m * 2 + 1] = unpool[2 * j + 1];
        }
    }
}

// ---------------------------------------------------------------------------
// F[bn][k] bf16: concat(x[963], xh[192], att[8], zeros) padded to KPAD2
// ---------------------------------------------------------------------------
__global__ void build_F(const float* __restrict__ x, const float* __restrict__ xh,
                        const float* __restrict__ att, ushort* __restrict__ F)
{
    int bn = blockIdx.x;
    for (int k = threadIdx.x; k < KPAD2; k += 256) {
        float v = 0.f;
        if (k < FEAT) v = x[(size_t)bn * FEAT + k];
        else if (k < FEAT + HID) v = xh[(size_t)bn * HID + (k - FEAT)];
        else if (k < IN_DIM) v = att[(size_t)bn * 8 + (k - FEAT - HID)];
        F[(size_t)bn * KPAD2 + k] = f2bf(v);
    }
}

// ---------------------------------------------------------------------------
// fused weight prep: entry Wt[384][KPAD2] then 13x res Wt[192][384]
// ---------------------------------------------------------------------------
#define WT_E_TOT (384 * KPAD2)
#define WT_R_TOT (13 * 192 * 384)
__global__ void prep_wt_all(const float* __restrict__ W_in, const float* __restrict__ loopW_in,
                            const float* __restrict__ res_W, const float* __restrict__ res_loopW,
                            const float* __restrict__ W_out, const float* __restrict__ loopW_out,
                            ushort* __restrict__ wt_e, ushort* __restrict__ wt_r)
{
    int idx = blockIdx.x * 256 + threadIdx.x;
    if (idx < WT_E_TOT) {
        int n = idx / KPAD2, k = idx % KPAD2;
        float v = 0.f;
        if (k < IN_DIM) v = (n < 192) ? W_in[k * 192 + n] : loopW_in[k * 192 + (n - 192)];
        wt_e[idx] = f2bf(v);
        return;
    }
    idx -= WT_E_TOT;
    if (idx >= WT_R_TOT) return;
    int l = idx / (192 * 384);
    int rem = idx % (192 * 384);
    int n = rem / 384, k2 = rem % 384;
    const float* W = (l < 12) ? (res_W + (size_t)l * 192 * 192) : W_out;
    const float* L = (l < 12) ? (res_loopW + (size_t)l * 192 * 192) : loopW_out;
    float v = (k2 < 192) ? W[k2 * 192 + n] : L[(k2 - 192) * 192 + n];
    wt_r[idx] = f2bf(v);
}

// ---------------------------------------------------------------------------
// entry GEMM, K-split x2: u2[M2,384] = F[M2,KPAD2] @ Wt^T.
// 512 thr (8 waves); block 64 rows x 192 cols; grid (155, 2).
// wave w: w&3 -> col group (4m x 3n), w>>2 -> k half (19 tiles each).
// High waves dump f32 partials to LDS; low waves add + store.
// ---------------------------------------------------------------------------
__global__ __launch_bounds__(512) void gemm_entry(
    const ushort* __restrict__ F, const ushort* __restrict__ Wt,
    ushort* __restrict__ u2)
{
    __shared__ float part[64 * 192];   // 48 KB

    int tid = threadIdx.x;
    int wave = tid >> 6, lane = tid & 63;
    int kh = wave >> 2, w4 = wave & 3;
    int lr = lane & 15, lkq = lane >> 4, lk = lkq * 8;
    int row0 = blockIdx.x * 64;
    int lnb = w4 * 48;                       // LDS/block-local col
    int nb = blockIdx.y * 192 + lnb;         // global col
    int tbeg = kh * EHALF, tend = tbeg + EHALF;

    int rows[4];
#pragma unroll
    for (int mt = 0; mt < 4; ++mt) {
        int r = row0 + mt * 16 + lr;
        rows[mt] = (r < M2) ? r : M2 - 1;
    }

    f32x4 acc[4][3];
#pragma unroll
    for (int mt = 0; mt < 4; ++mt)
#pragma unroll
        for (int nt = 0; nt < 3; ++nt) acc[mt][nt] = (f32x4){0.f, 0.f, 0.f, 0.f};

    bf16x8 a0[4], b0[3], a1[4], b1[3];
    auto LD = [&](int t, bf16x8 (&a)[4], bf16x8 (&b)[3]) {
#pragma unroll
        for (int mt = 0; mt < 4; ++mt)
            a[mt] = *(const bf16x8*)(F + (size_t)rows[mt] * KPAD2 + t * 32 + lk);
#pragma unroll
        for (int nt = 0; nt < 3; ++nt)
            b[nt] = *(const bf16x8*)(Wt + (size_t)(nb + nt * 16 + lr) * KPAD2 + t * 32 + lk);
    };
    auto MM = [&](bf16x8 (&a)[4], bf16x8 (&b)[3]) {
#pragma unroll
        for (int mt = 0; mt < 4; ++mt)
#pragma unroll
            for (int nt = 0; nt < 3; ++nt)
                acc[mt][nt] = __builtin_amdgcn_mfma_f32_16x16x32_bf16(a[mt], b[nt], acc[mt][nt], 0, 0, 0);
    };

    LD(tbeg, a0, b0);
    for (int t = tbeg; t < tend; t += 2) {
        if (t + 1 < tend) LD(t + 1, a1, b1);
        MM(a0, b0);
        if (t + 2 < tend) LD(t + 2, a0, b0);
        if (t + 1 < tend) MM(a1, b1);
    }

    int crow = lkq * 4;
    if (kh == 1) {
#pragma unroll
        for (int mt = 0; mt < 4; ++mt)
#pragma unroll
            for (int r = 0; r < 4; ++r)
#pragma unroll
                for (int nt = 0; nt < 3; ++nt)
                    part[(mt * 16 + crow + r) * 192 + lnb + nt * 16 + lr] = acc[mt][nt][r];
    }
    __syncthreads();
    if (kh == 0) {
#pragma unroll
        for (int mt = 0; mt < 4; ++mt)
#pragma unroll
            for (int r = 0; r < 4; ++r) {
                int orow = row0 + mt * 16 + crow + r;
                if (orow < M2) {
#pragma unroll
                    for (int nt = 0; nt < 3; ++nt) {
                        float s = acc[mt][nt][r] + part[(mt * 16 + crow + r) * 192 + lnb + nt * 16 + lr];
                        u2[(size_t)orow * 384 + nb + nt * 16 + lr] = f2bf(s);
                    }
                }
            }
    }
}

// ---------------------------------------------------------------------------
// entry combine: h = relu( sum_i ew*Pw[eidx] + mid(Pl over sidx) + bias )
// 192 thr = 8 rows x 24 col-groups of 8 (16B vector loads). XCD-swizzled.
// ---------------------------------------------------------------------------
__global__ void combine_entry(const ushort* __restrict__ u2, const int* __restrict__ eidx,
                              const float* __restrict__ ew, const int* __restrict__ sidx,
                              const float* __restrict__ bias, ushort* __restrict__ h)
{
    int lb = xcd_swz(blockIdx.x, gridDim.x);
    int tid = threadIdx.x;
    int rloc = tid / 24, f8 = tid % 24;
    int bm = lb * 8 + rloc;
    if (bm >= MTOT) return;
    int b = bm / N3V, n = bm % N3V;
    const ushort* base = u2 + (size_t)b * N2V * 384;

    float acc[8];
#pragma unroll
    for (int e = 0; e < 8; ++e) acc[e] = 0.f;
#pragma unroll
    for (int i = 0; i < 12; ++i) {
        float w = ew[n * 12 + i];
        bf16x8 v = *(const bf16x8*)(base + (size_t)eidx[n * 12 + i] * 384 + f8 * 8);
#pragma unroll
        for (int e = 0; e < 8; ++e) acc[e] += w * bf2f((ushort)v[e]);
    }
    int p0 = sidx[n * 2], p1 = sidx[n * 2 + 1];
    bf16x8 s0 = *(const bf16x8*)(base + (size_t)p0 * 384 + 192 + f8 * 8);
    if (p1 >= 0) {
        bf16x8 s1 = *(const bf16x8*)(base + (size_t)p1 * 384 + 192 + f8 * 8);
#pragma unroll
        for (int e = 0; e < 8; ++e) acc[e] += 0.5f * (bf2f((ushort)s0[e]) + bf2f((ushort)s1[e]));
    } else {
#pragma unroll
        for (int e = 0; e < 8; ++e) acc[e] += bf2f((ushort)s0[e]);
    }
    bf16x8 o;
#pragma unroll
    for (int e = 0; e < 8; ++e)
        o[e] = (short)f2bf(fmaxf(acc[e] + bias[f8 * 8 + e], 0.f));
    *(bf16x8*)(h + (size_t)bm * 192 + f8 * 8) = o;
}

// ---------------------------------------------------------------------------
// spmv: g = adj @ h  (branchless 6-point gather, 16B loads). XCD-swizzled.
// ---------------------------------------------------------------------------
__global__ void spmv_g(const ushort* __restrict__ h, const int* __restrict__ cols,
                       const float* __restrict__ vals, ushort* __restrict__ g)
{
    int lb = xcd_swz(blockIdx.x, gridDim.x);
    int tid = threadIdx.x;
    int rloc = tid / 24, f8 = tid % 24;
    int bm = lb * 8 + rloc;
    if (bm >= MTOT) return;
    int b = bm / N3V, m = bm % N3V;
    const ushort* hb = h + (size_t)b * N3V * 192;

    float acc[8];
#pragma unroll
    for (int e = 0; e < 8; ++e) acc[e] = 0.f;
#pragma unroll
    for (int j = 0; j < 6; ++j) {
        float w = vals[m * 6 + j];
        bf16x8 v = *(const bf16x8*)(hb + (size_t)cols[m * 6 + j] * 192 + f8 * 8);
#pragma unroll
        for (int e = 0; e < 8; ++e) acc[e] += w * bf2f((ushort)v[e]);
    }
    bf16x8 o;
#pragma unroll
    for (int e = 0; e < 8; ++e) o[e] = (short)f2bf(acc[e]);
    *(bf16x8*)(g + (size_t)bm * 192 + f8 * 8) = o;
}

// ---------------------------------------------------------------------------
// res GConv GEMM, K-split x2: out = act( [g|sx] @ Wt^T + bias )
// 512 thr (8 waves); block 32 rows x 192 cols; grid 1233.
// wave w: w&3 -> col group (2m x 3n), w>>2 -> k half (0:g half, 1:sx half).
// High waves dump f32 partials to 24KB LDS; low waves add + epilogue.
// ACT 0: relu; ACT 1: 0.5*(hprev + relu(.)). XCD-swizzled.
// ---------------------------------------------------------------------------
template <int ACT>
__global__ __launch_bounds__(512) void gconv_res(
    const ushort* __restrict__ g, const ushort* __restrict__ sx,
    const ushort* __restrict__ Wt, const float* __restrict__ bias,
    const ushort* __restrict__ hprev, ushort* __restrict__ outp)
{
    __shared__ float part[32 * 192];   // 24 KB

    int lb = xcd_swz(blockIdx.x, gridDim.x);
    int tid = threadIdx.x;
    int wave = tid >> 6, lane = tid & 63;
    int kh = wave >> 2, w4 = wave & 3;
    int lr = lane & 15, lkq = lane >> 4, lk = lkq * 8;
    int row0 = lb * 32;
    int nb = w4 * 48;

    int rows[2] = { row0 + lr, row0 + 16 + lr };
    const ushort* asrc = kh ? sx : g;
    int kwoff = kh * 192;                 // Wt k-offset for this half

    f32x4 acc[2][3];
#pragma unroll
    for (int mt = 0; mt < 2; ++mt)
#pragma unroll
        for (int nt = 0; nt < 3; ++nt) acc[mt][nt] = (f32x4){0.f, 0.f, 0.f, 0.f};

    bf16x8 a0[2], b0[3], a1[2], b1[3];
    auto LD = [&](int t, bf16x8 (&a)[2], bf16x8 (&b)[3]) {
        int kk = t * 32 + lk;
#pragma unroll
        for (int mt = 0; mt < 2; ++mt)
            a[mt] = *(const bf16x8*)(asrc + (size_t)rows[mt] * 192 + kk);
#pragma unroll
        for (int nt = 0; nt < 3; ++nt)
            b[nt] = *(const bf16x8*)(Wt + (size_t)(nb + nt * 16 + lr) * 384 + kwoff + kk);
    };
    auto MM = [&](bf16x8 (&a)[2], bf16x8 (&b)[3]) {
#pragma unroll
        for (int mt = 0; mt < 2; ++mt)
#pragma unroll
            for (int nt = 0; nt < 3; ++nt)
                acc[mt][nt] = __builtin_amdgcn_mfma_f32_16x16x32_bf16(a[mt], b[nt], acc[mt][nt], 0, 0, 0);
    };

    LD(0, a0, b0);
#pragma unroll
    for (int t = 0; t < 6; t += 2) {
        if (t + 1 < 6) LD(t + 1, a1, b1);
        MM(a0, b0);
        if (t + 2 < 6) LD(t + 2, a0, b0);
        if (t + 1 < 6) MM(a1, b1);
    }

    int crow = lkq * 4;
    if (kh == 1) {
#pragma unroll
        for (int mt = 0; mt < 2; ++mt)
#pragma unroll
            for (int r = 0; r < 4; ++r)
#pragma unroll
                for (int nt = 0; nt < 3; ++nt)
                    part[(mt * 16 + crow + r) * 192 + nb + nt * 16 + lr] = acc[mt][nt][r];
    }
    __syncthreads();
    if (kh == 0) {
#pragma unroll
        for (int mt = 0; mt < 2; ++mt)
#pragma unroll
            for (int r = 0; r < 4; ++r) {
                int orow = row0 + mt * 16 + crow + r;
#pragma unroll
                for (int nt = 0; nt < 3; ++nt) {
                    int nn = nb + nt * 16 + lr;
                    float s = acc[mt][nt][r] + part[(mt * 16 + crow + r) * 192 + nn] + bias[nn];
                    s = fmaxf(s, 0.f);
                    if (ACT) s = 0.5f * (bf2f(hprev[(size_t)orow * 192 + nn]) + s);
                    outp[(size_t)orow * 192 + nn] = f2bf(s);
                }
            }
    }
}

// ---------------------------------------------------------------------------
// final head: block = 64 rows x 4 subs; each sub handles 48 k; quad shfl reduce
// ---------------------------------------------------------------------------
__global__ void head_a2(const ushort* __restrict__ y, const float* __restrict__ Wg,
                        const float* __restrict__ loopWg, float* __restrict__ t)
{
    int tid = threadIdx.x;
    int rloc = tid >> 2, sub = tid & 3;
    int bm = blockIdx.x * 64 + rloc;
    if (bm >= MTOT) return;
    float s[6];
#pragma unroll
    for (int c = 0; c < 6; ++c) s[c] = 0.f;
#pragma unroll
    for (int kk = 0; kk < 6; ++kk) {
        int kg = sub * 6 + kk;
        bf16x8 v = *(const bf16x8*)(y + (size_t)bm * 192 + kg * 8);
#pragma unroll
        for (int e = 0; e < 8; ++e) {
            float f = bf2f((ushort)v[e]);
            int k = kg * 8 + e;
            s[0] += f * Wg[k * 3 + 0];
            s[1] += f * Wg[k * 3 + 1];
            s[2] += f * Wg[k * 3 + 2];
            s[3] += f * loopWg[k * 3 + 0];
            s[4] += f * loopWg[k * 3 + 1];
            s[5] += f * loopWg[k * 3 + 2];
        }
    }
#pragma unroll
    for (int o = 1; o <= 2; o <<= 1)
#pragma unroll
        for (int c = 0; c < 6; ++c) s[c] += __shfl_xor(s[c], o);
    if (sub == 0) {
#pragma unroll
        for (int c = 0; c < 6; ++c) t[(size_t)bm * 6 + c] = s[c];
    }
}

__global__ void head_b(const float* __restrict__ t, const int* __restrict__ cols,
                       const float* __restrict__ vals, const float* __restrict__ bg,
                       float* __restrict__ out)
{
    int idx = blockIdx.x * 256 + threadIdx.x;
    if (idx >= MTOT * 3) return;
    int bm = idx / 3, c = idx % 3;
    int b = bm / N3V, m = bm % N3V;
    float s = 0.f;
#pragma unroll
    for (int j = 0; j < 6; ++j)
        s += vals[m * 6 + j] * t[((size_t)b * N3V + cols[m * 6 + j]) * 6 + c];
    s += t[(size_t)bm * 6 + 3 + c] + bg[c];
    out[idx] = s;
}

// ---------------------------------------------------------------------------
extern "C" void kernel_launch(void* const* d_in, const int* in_sizes, int n_in,
                              void* d_out, int out_size, void* d_ws, size_t ws_size,
                              hipStream_t stream)
{
    const float* x        = (const float*)d_in[0];
    const float* x2       = (const float*)d_in[1];
    const float* xh       = (const float*)d_in[2];
    const float* Wq       = (const float*)d_in[3];
    const float* bq       = (const float*)d_in[4];
    const float* Wk       = (const float*)d_in[5];
    const float* bk       = (const float*)d_in[6];
    const float* Wv       = (const float*)d_in[7];
    const float* bv       = (const float*)d_in[8];
    const float* adj      = (const float*)d_in[9];
    const int*   unpool   = (const int*)d_in[10];
    const float* W_in     = (const float*)d_in[11];
    const float* loopW_in = (const float*)d_in[12];
    const float* b_in     = (const float*)d_in[13];
    const float* res_W    = (const float*)d_in[14];
    const float* res_loopW= (const float*)d_in[15];
    const float* res_b    = (const float*)d_in[16];
    const float* W_out    = (const float*)d_in[17];
    const float* loopW_out= (const float*)d_in[18];
    const float* b_out    = (const float*)d_in[19];
    const float* Wg       = (const float*)d_in[20];
    const float* loopWg   = (const float*)d_in[21];
    const float* bg       = (const float*)d_in[22];
    float* out = (float*)d_out;

    char* ws = (char*)d_ws;
    size_t o = 0;
    auto alloc = [&](size_t bytes) { char* p = ws + o; o += (bytes + 255) & ~(size_t)255; return p; };
    float*  q    = (float*)alloc((size_t)M2 * 8 * 4);
    float*  kbuf = (float*)alloc((size_t)M2 * 8 * 4);
    float*  vbuf = (float*)alloc((size_t)M2 * 8 * 4);
    float*  att  = (float*)alloc((size_t)M2 * 8 * 4);
    int*    cols = (int*)alloc((size_t)N3V * 6 * 4);
    float*  vals = (float*)alloc((size_t)N3V * 6 * 4);
    int*    eidx = (int*)alloc((size_t)N3V * 12 * 4);
    float*  ewgt = (float*)alloc((size_t)N3V * 12 * 4);
    int*    sidx = (int*)alloc((size_t)N3V * 2 * 4);
    ushort* F    = (ushort*)alloc((size_t)M2 * KPAD2 * 2);
    ushort* wt_e = (ushort*)alloc((size_t)384 * KPAD2 * 2);
    ushort* wt_r = (ushort*)alloc((size_t)13 * 192 * 384 * 2);
    ushort* u2   = (ushort*)alloc((size_t)M2 * 384 * 2);
    ushort* g    = (ushort*)alloc((size_t)MTOT * 192 * 2);
    ushort* h    = (ushort*)alloc((size_t)MTOT * 192 * 2);
    ushort* h2   = (ushort*)alloc((size_t)MTOT * 192 * 2);
    ushort* y    = (ushort*)alloc((size_t)MTOT * 192 * 2);
    float*  ts   = (float*)alloc((size_t)MTOT * 6 * 4);
    if (ws_size < o) return;

    qkv_kernel<<<(M2 + 255) / 256, 256, 0, stream>>>(x2, Wq, bq, Wk, bk, Wv, bv, q, kbuf, vbuf);
    attn_kernel2<<<dim3(NB, 10), 256, 0, stream>>>(q, kbuf, vbuf, att);
    adj_prep<<<N3V, 256, 0, stream>>>(adj, unpool, cols, vals, eidx, ewgt, sidx);
    build_F<<<M2, 256, 0, stream>>>(x, xh, att, F);
    prep_wt_all<<<(WT_E_TOT + WT_R_TOT + 255) / 256, 256, 0, stream>>>(
        W_in, loopW_in, res_W, res_loopW, W_out, loopW_out, wt_e, wt_r);

    // entry: u2 = F @ [W_in | loopW_in]   (M=9888, K=1216, k-split x2)
    gemm_entry<<<dim3((M2 + 63) / 64, 2), 512, 0, stream>>>(F, wt_e, u2);
    combine_entry<<<(MTOT + 7) / 8, 192, 0, stream>>>(u2, eidx, ewgt, sidx, b_in, h);

    int gg = MTOT / 32;              // 1233
    int gs = (MTOT + 7) / 8;         // 4932
    ushort* cur = h;
    ushort* nxt = h2;
    for (int i = 0; i < 6; ++i) {
        const float* B0 = res_b + (size_t)(i * 2 + 0) * 192;
        const float* B1 = res_b + (size_t)(i * 2 + 1) * 192;
        const ushort* W0 = wt_r + (size_t)(i * 2 + 0) * 192 * 384;
        const ushort* W1 = wt_r + (size_t)(i * 2 + 1) * 192 * 384;
        spmv_g<<<gs, 192, 0, stream>>>(cur, cols, vals, g);
        gconv_res<0><<<gg, 512, 0, stream>>>(g, cur, W0, B0, nullptr, y);
        spmv_g<<<gs, 192, 0, stream>>>(y, cols, vals, g);
        gconv_res<1><<<gg, 512, 0, stream>>>(g, y, W1, B1, cur, nxt);
        ushort* tmp = cur; cur = nxt; nxt = tmp;
    }

    // out conv (relu)
    spmv_g<<<gs, 192, 0, stream>>>(cur, cols, vals, g);
    gconv_res<0><<<gg, 512, 0, stream>>>(g, cur,
        wt_r + (size_t)12 * 192 * 384, b_out, nullptr, y);

    head_a2<<<(MTOT + 63) / 64, 256, 0, stream>>>(y, Wg, loopWg, ts);
    head_b<<<(MTOT * 3 + 255) / 256, 256, 0, stream>>>(ts, cols, vals, bg, out);
}

// Round 11
// 652.148 us; speedup vs baseline: 1.1797x; 1.1797x over previous
//
#include <hip/hip_runtime.h>
#include <hip/hip_bf16.h>

#define NB 16
#define N2V 618
#define N3V 2466
#define FEAT 963
#define HID 192
#define IN_DIM 1163
#define KPAD2 1216         // 1163 padded to 38*32
#define ETILES 38
#define EHALF 19
#define MTOT (NB * N3V)    // 39456
#define M2   (NB * N2V)    // 9888

typedef __attribute__((ext_vector_type(8))) short bf16x8;
typedef __attribute__((ext_vector_type(4))) float f32x4;

__device__ __forceinline__ float bf2f(ushort u) {
    return __uint_as_float(((unsigned)u) << 16);
}
__device__ __forceinline__ ushort f2bf(float f) {   // round-to-nearest-even
    unsigned u = __float_as_uint(f);
    return (ushort)((u + 0x7FFFu + ((u >> 16) & 1u)) >> 16);
}
// bijective XCD-chunk swizzle (m204)
__device__ __forceinline__ int xcd_swz(int bid, int G) {
    int q = G >> 3, r = G & 7;
    int xcd = bid & 7, slot = bid >> 3;
    return (xcd < r) ? xcd * (q + 1) + slot : r * (q + 1) + (xcd - r) * q + slot;
}

// ---------------------------------------------------------------------------
// q,k,v projections: mv grade-1 only -> rows 1..3 of W
// ---------------------------------------------------------------------------
__global__ void qkv_kernel(const float* __restrict__ x2,
                           const float* __restrict__ Wq, const float* __restrict__ bq,
                           const float* __restrict__ Wk, const float* __restrict__ bk,
                           const float* __restrict__ Wv, const float* __restrict__ bv,
                           float* __restrict__ q, float* __restrict__ k, float* __restrict__ v)
{
    int idx = blockIdx.x * 256 + threadIdx.x;
    if (idx >= M2) return;
    float c0 = x2[idx * 3 + 0], c1 = x2[idx * 3 + 1], c2 = x2[idx * 3 + 2];
#pragma unroll
    for (int d = 0; d < 8; ++d) {
        q[idx * 8 + d] = bq[d] + c0 * Wq[8 + d] + c1 * Wq[16 + d] + c2 * Wq[24 + d];
        k[idx * 8 + d] = bk[d] + c0 * Wk[8 + d] + c1 * Wk[16 + d] + c2 * Wk[24 + d];
        v[idx * 8 + d] = bv[d] + c0 * Wv[8 + d] + c1 * Wv[16 + d] + c2 * Wv[24 + d];
    }
}

// ---------------------------------------------------------------------------
// attention: block = (batch, 64 queries); K,V staged in LDS (39.6KB);
// 4 lanes per query, online softmax, shfl merge across the 4 sub-lanes.
// ---------------------------------------------------------------------------
__global__ __launch_bounds__(256) void attn_kernel2(const float* __restrict__ q,
                                                    const float* __restrict__ k,
                                                    const float* __restrict__ v,
                                                    float* __restrict__ att)
{
    __shared__ float4 kv[N2V * 4];            // K: [0,2*N2V), V: [2*N2V,4*N2V)
    int b = blockIdx.x, qb = blockIdx.y;
    const float4* k4 = (const float4*)(k + (size_t)b * N2V * 8);
    const float4* v4 = (const float4*)(v + (size_t)b * N2V * 8);
    for (int i = threadIdx.x; i < N2V * 2; i += 256) {
        kv[i] = k4[i];
        kv[N2V * 2 + i] = v4[i];
    }
    __syncthreads();

    int ql = threadIdx.x >> 2, sub = threadIdx.x & 3;
    int qi = qb * 64 + ql;
    bool valid = qi < N2V;
    float qv[8];
#pragma unroll
    for (int d = 0; d < 8; ++d) qv[d] = 0.f;
    if (valid) {
#pragma unroll
        for (int d = 0; d < 8; ++d) qv[d] = q[((size_t)b * N2V + qi) * 8 + d];
    }

    const float scale = 0.35355339059327373f;
    float m = -3.0e38f, lsum = 0.f, acc[8];
#pragma unroll
    for (int d = 0; d < 8; ++d) acc[d] = 0.f;

    for (int kk = sub; kk < N2V; kk += 4) {
        float4 k0 = kv[kk * 2], k1 = kv[kk * 2 + 1];
        float s = qv[0] * k0.x + qv[1] * k0.y + qv[2] * k0.z + qv[3] * k0.w
                + qv[4] * k1.x + qv[5] * k1.y + qv[6] * k1.z + qv[7] * k1.w;
        s *= scale;
        float nm = fmaxf(m, s);
        float corr = __expf(m - nm);
        float p = __expf(s - nm);
        lsum = lsum * corr + p;
        float4 v0 = kv[N2V * 2 + kk * 2], v1 = kv[N2V * 2 + kk * 2 + 1];
        acc[0] = acc[0] * corr + p * v0.x; acc[1] = acc[1] * corr + p * v0.y;
        acc[2] = acc[2] * corr + p * v0.z; acc[3] = acc[3] * corr + p * v0.w;
        acc[4] = acc[4] * corr + p * v1.x; acc[5] = acc[5] * corr + p * v1.y;
        acc[6] = acc[6] * corr + p * v1.z; acc[7] = acc[7] * corr + p * v1.w;
        m = nm;
    }
#pragma unroll
    for (int o = 1; o <= 2; o <<= 1) {
        float m2 = __shfl_xor(m, o);
        float l2 = __shfl_xor(lsum, o);
        float nm = fmaxf(m, m2);
        float c1 = __expf(m - nm), c2 = __expf(m2 - nm);
        lsum = lsum * c1 + l2 * c2;
#pragma unroll
        for (int d = 0; d < 8; ++d) {
            float a2 = __shfl_xor(acc[d], o);
            acc[d] = acc[d] * c1 + a2 * c2;
        }
        m = nm;
    }
    if (valid && sub == 0) {
#pragma unroll
        for (int d = 0; d < 8; ++d)
            att[((size_t)b * N2V + qi) * 8 + d] = acc[d] / lsum;
    }
}

// ---------------------------------------------------------------------------
// adjacency prep: <=6 (col,val) per row (sorted), plus entry-layer expansion
// through the unpool midpoints (adj@Up, <=12 gathers) and self parent pair.
// ---------------------------------------------------------------------------
__global__ void adj_prep(const float* __restrict__ adj, const int* __restrict__ unpool,
                         int* __restrict__ cols, float* __restrict__ vals,
                         int* __restrict__ eidx, float* __restrict__ ew,
                         int* __restrict__ sidx)
{
    int m = blockIdx.x;
    __shared__ int cnt;
    __shared__ int lc[8];
    __shared__ float lv[8];
    if (threadIdx.x == 0) cnt = 0;
    __syncthreads();
    for (int c = threadIdx.x; c < N3V; c += 256) {
        float a = adj[(size_t)m * N3V + c];
        if (a != 0.f) {
            int p = atomicAdd(&cnt, 1);
            if (p < 6) { lc[p] = c; lv[p] = a; }
        }
    }
    __syncthreads();
    if (threadIdx.x == 0) {
        int n = cnt < 6 ? cnt : 6;
        for (int i = 1; i < n; ++i) {
            int ci = lc[i]; float vi = lv[i]; int j = i - 1;
            while (j >= 0 && lc[j] > ci) { lc[j + 1] = lc[j]; lv[j + 1] = lv[j]; --j; }
            lc[j + 1] = ci; lv[j + 1] = vi;
        }
        int ne = 0;
        for (int i = 0; i < 6; ++i) {
            int c = (i < n) ? lc[i] : 0;
            float w = (i < n) ? lv[i] : 0.f;
            cols[m * 6 + i] = c;
            vals[m * 6 + i] = w;
            if (i < n) {
                if (c < N2V) { eidx[m * 12 + ne] = c; ew[m * 12 + ne] = w; ++ne; }
                else {
                    int jj = c - N2V;
                    eidx[m * 12 + ne] = unpool[2 * jj];     ew[m * 12 + ne] = 0.5f * w; ++ne;
                    eidx[m * 12 + ne] = unpool[2 * jj + 1]; ew[m * 12 + ne] = 0.5f * w; ++ne;
                }
            }
        }
        for (; ne < 12; ++ne) { eidx[m * 12 + ne] = 0; ew[m * 12 + ne] = 0.f; }
        if (m < N2V) { sidx[m * 2] = m; sidx[m * 2 + 1] = -1; }
        else {
            int j = m - N2V;
            sidx[m * 2] = unpool[2 * j];
            sidx[m * 2 + 1] = unpool[2 * j + 1];
        }
    }
}

// ---------------------------------------------------------------------------
// F[bn][k] bf16: concat(x[963], xh[192], att[8], zeros) padded to KPAD2
// ---------------------------------------------------------------------------
__global__ void build_F(const float* __restrict__ x, const float* __restrict__ xh,
                        const float* __restrict__ att, ushort* __restrict__ F)
{
    int bn = blockIdx.x;
    for (int k = threadIdx.x; k < KPAD2; k += 256) {
        float v = 0.f;
        if (k < FEAT) v = x[(size_t)bn * FEAT + k];
        else if (k < FEAT + HID) v = xh[(size_t)bn * HID + (k - FEAT)];
        else if (k < IN_DIM) v = att[(size_t)bn * 8 + (k - FEAT - HID)];
        F[(size_t)bn * KPAD2 + k] = f2bf(v);
    }
}

// ---------------------------------------------------------------------------
// fused weight prep: entry Wt[384][KPAD2] then 13x res Wt[192][384]
// ---------------------------------------------------------------------------
#define WT_E_TOT (384 * KPAD2)
#define WT_R_TOT (13 * 192 * 384)
__global__ void prep_wt_all(const float* __restrict__ W_in, const float* __restrict__ loopW_in,
                            const float* __restrict__ res_W, const float* __restrict__ res_loopW,
                            const float* __restrict__ W_out, const float* __restrict__ loopW_out,
                            ushort* __restrict__ wt_e, ushort* __restrict__ wt_r)
{
    int idx = blockIdx.x * 256 + threadIdx.x;
    if (idx < WT_E_TOT) {
        int n = idx / KPAD2, k = idx % KPAD2;
        float v = 0.f;
        if (k < IN_DIM) v = (n < 192) ? W_in[k * 192 + n] : loopW_in[k * 192 + (n - 192)];
        wt_e[idx] = f2bf(v);
        return;
    }
    idx -= WT_E_TOT;
    if (idx >= WT_R_TOT) return;
    int l = idx / (192 * 384);
    int rem = idx % (192 * 384);
    int n = rem / 384, k2 = rem % 384;
    const float* W = (l < 12) ? (res_W + (size_t)l * 192 * 192) : W_out;
    const float* L = (l < 12) ? (res_loopW + (size_t)l * 192 * 192) : loopW_out;
    float v = (k2 < 192) ? W[k2 * 192 + n] : L[(k2 - 192) * 192 + n];
    wt_r[idx] = f2bf(v);
}

// ---------------------------------------------------------------------------
// entry GEMM, K-split x2: u2[M2,384] = F[M2,KPAD2] @ Wt^T.
// 512 thr (8 waves); block 64 rows x 192 cols; grid (155, 2).
// wave w: w&3 -> col group (4m x 3n), w>>2 -> k half (19 tiles each).
// High waves dump f32 partials to LDS; low waves add + store.
// ---------------------------------------------------------------------------
__global__ __launch_bounds__(512) void gemm_entry(
    const ushort* __restrict__ F, const ushort* __restrict__ Wt,
    ushort* __restrict__ u2)
{
    __shared__ float part[64 * 192];   // 48 KB

    int tid = threadIdx.x;
    int wave = tid >> 6, lane = tid & 63;
    int kh = wave >> 2, w4 = wave & 3;
    int lr = lane & 15, lkq = lane >> 4, lk = lkq * 8;
    int row0 = blockIdx.x * 64;
    int lnb = w4 * 48;                       // LDS/block-local col
    int nb = blockIdx.y * 192 + lnb;         // global col
    int tbeg = kh * EHALF, tend = tbeg + EHALF;

    int rows[4];
#pragma unroll
    for (int mt = 0; mt < 4; ++mt) {
        int r = row0 + mt * 16 + lr;
        rows[mt] = (r < M2) ? r : M2 - 1;
    }

    f32x4 acc[4][3];
#pragma unroll
    for (int mt = 0; mt < 4; ++mt)
#pragma unroll
        for (int nt = 0; nt < 3; ++nt) acc[mt][nt] = (f32x4){0.f, 0.f, 0.f, 0.f};

    bf16x8 a0[4], b0[3], a1[4], b1[3];
    auto LD = [&](int t, bf16x8 (&a)[4], bf16x8 (&b)[3]) {
#pragma unroll
        for (int mt = 0; mt < 4; ++mt)
            a[mt] = *(const bf16x8*)(F + (size_t)rows[mt] * KPAD2 + t * 32 + lk);
#pragma unroll
        for (int nt = 0; nt < 3; ++nt)
            b[nt] = *(const bf16x8*)(Wt + (size_t)(nb + nt * 16 + lr) * KPAD2 + t * 32 + lk);
    };
    auto MM = [&](bf16x8 (&a)[4], bf16x8 (&b)[3]) {
#pragma unroll
        for (int mt = 0; mt < 4; ++mt)
#pragma unroll
            for (int nt = 0; nt < 3; ++nt)
                acc[mt][nt] = __builtin_amdgcn_mfma_f32_16x16x32_bf16(a[mt], b[nt], acc[mt][nt], 0, 0, 0);
    };

    LD(tbeg, a0, b0);
    for (int t = tbeg; t < tend; t += 2) {
        if (t + 1 < tend) LD(t + 1, a1, b1);
        MM(a0, b0);
        if (t + 2 < tend) LD(t + 2, a0, b0);
        if (t + 1 < tend) MM(a1, b1);
    }

    int crow = lkq * 4;
    if (kh == 1) {
#pragma unroll
        for (int mt = 0; mt < 4; ++mt)
#pragma unroll
            for (int r = 0; r < 4; ++r)
#pragma unroll
                for (int nt = 0; nt < 3; ++nt)
                    part[(mt * 16 + crow + r) * 192 + lnb + nt * 16 + lr] = acc[mt][nt][r];
    }
    __syncthreads();
    if (kh == 0) {
#pragma unroll
        for (int mt = 0; mt < 4; ++mt)
#pragma unroll
            for (int r = 0; r < 4; ++r) {
                int orow = row0 + mt * 16 + crow + r;
                if (orow < M2) {
#pragma unroll
                    for (int nt = 0; nt < 3; ++nt) {
                        float s = acc[mt][nt][r] + part[(mt * 16 + crow + r) * 192 + lnb + nt * 16 + lr];
                        u2[(size_t)orow * 384 + nb + nt * 16 + lr] = f2bf(s);
                    }
                }
            }
    }
}

// ---------------------------------------------------------------------------
// entry combine: h = relu( sum_i ew*Pw[eidx] + mid(Pl over sidx) + bias )
// 192 thr = 8 rows x 24 col-groups of 8 (16B vector loads). XCD-swizzled.
// ---------------------------------------------------------------------------
__global__ void combine_entry(const ushort* __restrict__ u2, const int* __restrict__ eidx,
                              const float* __restrict__ ew, const int* __restrict__ sidx,
                              const float* __restrict__ bias, ushort* __restrict__ h)
{
    int lb = xcd_swz(blockIdx.x, gridDim.x);
    int tid = threadIdx.x;
    int rloc = tid / 24, f8 = tid % 24;
    int bm = lb * 8 + rloc;
    if (bm >= MTOT) return;
    int b = bm / N3V, n = bm % N3V;
    const ushort* base = u2 + (size_t)b * N2V * 384;

    float acc[8];
#pragma unroll
    for (int e = 0; e < 8; ++e) acc[e] = 0.f;
#pragma unroll
    for (int i = 0; i < 12; ++i) {
        float w = ew[n * 12 + i];
        bf16x8 v = *(const bf16x8*)(base + (size_t)eidx[n * 12 + i] * 384 + f8 * 8);
#pragma unroll
        for (int e = 0; e < 8; ++e) acc[e] += w * bf2f((ushort)v[e]);
    }
    int p0 = sidx[n * 2], p1 = sidx[n * 2 + 1];
    bf16x8 s0 = *(const bf16x8*)(base + (size_t)p0 * 384 + 192 + f8 * 8);
    if (p1 >= 0) {
        bf16x8 s1 = *(const bf16x8*)(base + (size_t)p1 * 384 + 192 + f8 * 8);
#pragma unroll
        for (int e = 0; e < 8; ++e) acc[e] += 0.5f * (bf2f((ushort)s0[e]) + bf2f((ushort)s1[e]));
    } else {
#pragma unroll
        for (int e = 0; e < 8; ++e) acc[e] += bf2f((ushort)s0[e]);
    }
    bf16x8 o;
#pragma unroll
    for (int e = 0; e < 8; ++e)
        o[e] = (short)f2bf(fmaxf(acc[e] + bias[f8 * 8 + e], 0.f));
    *(bf16x8*)(h + (size_t)bm * 192 + f8 * 8) = o;
}

// ---------------------------------------------------------------------------
// fused res GConv: out = act( [adj@src | src] @ Wt^T + bias )
// 512 thr, 32-row block, grid 1233 (XCD-swizzled).
// Phase 0: 768 gather tasks (1.5/thread) -> g staged in 12KB XOR-swizzled LDS.
// Phase 1: K-split GEMM: waves 0-3 A=LDS(g), waves 4-7 A=src rows (L2);
//          col group = (wave&3)*48, 2m x 3n; f32 partial reduce in 24KB LDS.
// ACT 0: relu; ACT 1: 0.5*(hprev + relu(.)).
// ---------------------------------------------------------------------------
template <int ACT>
__global__ __launch_bounds__(512) void gconv_fused(
    const ushort* __restrict__ src, const int* __restrict__ cols,
    const float* __restrict__ vals, const ushort* __restrict__ Wt,
    const float* __restrict__ bias, const ushort* __restrict__ hprev,
    ushort* __restrict__ outp)
{
    __shared__ ushort gs[32 * 192];    // 12 KB, XOR-swizzled
    __shared__ float part[32 * 192];   // 24 KB

    int lb = xcd_swz(blockIdx.x, gridDim.x);
    int tid = threadIdx.x;
    int row0 = lb * 32;                // MTOT % 32 == 0: no bounds checks

    // ---- phase 0: g = adj @ src for this block's 32 rows -> LDS ----
    for (int task = tid; task < 768; task += 512) {
        int r = task / 24, f8 = task % 24;
        int bm = row0 + r;
        int b = bm / N3V, m = bm % N3V;
        const ushort* hb = src + (size_t)b * N3V * 192;
        float acc[8];
#pragma unroll
        for (int e = 0; e < 8; ++e) acc[e] = 0.f;
#pragma unroll
        for (int j = 0; j < 6; ++j) {
            float w = vals[m * 6 + j];
            bf16x8 v = *(const bf16x8*)(hb + (size_t)cols[m * 6 + j] * 192 + f8 * 8);
#pragma unroll
            for (int e = 0; e < 8; ++e) acc[e] += w * bf2f((ushort)v[e]);
        }
        bf16x8 o;
#pragma unroll
        for (int e = 0; e < 8; ++e) o[e] = (short)f2bf(acc[e]);
        int byte = r * 384 + f8 * 16;
        byte ^= (r & 7) << 4;
        *(bf16x8*)((char*)gs + byte) = o;
    }
    __syncthreads();

    // ---- phase 1: GEMM ----
    int wave = tid >> 6, lane = tid & 63;
    int kh = wave >> 2, w4 = wave & 3;
    int lr = lane & 15, lkq = lane >> 4, lk = lkq * 8;
    int nb = w4 * 48;
    int rows[2] = { row0 + lr, row0 + 16 + lr };
    int kwoff = kh * 192;

    f32x4 acc[2][3];
#pragma unroll
    for (int mt = 0; mt < 2; ++mt)
#pragma unroll
        for (int nt = 0; nt < 3; ++nt) acc[mt][nt] = (f32x4){0.f, 0.f, 0.f, 0.f};

    bf16x8 a0[2], b0[3], a1[2], b1[3];
    auto LD = [&](int t, bf16x8 (&a)[2], bf16x8 (&b)[3]) {
        if (kh == 0) {
#pragma unroll
            for (int mt = 0; mt < 2; ++mt) {
                int rr = mt * 16 + lr;
                int byte = rr * 384 + t * 64 + lkq * 16;
                byte ^= (rr & 7) << 4;
                a[mt] = *(const bf16x8*)((const char*)gs + byte);
            }
        } else {
            int kk = t * 32 + lk;
#pragma unroll
            for (int mt = 0; mt < 2; ++mt)
                a[mt] = *(const bf16x8*)(src + (size_t)rows[mt] * 192 + kk);
        }
#pragma unroll
        for (int nt = 0; nt < 3; ++nt)
            b[nt] = *(const bf16x8*)(Wt + (size_t)(nb + nt * 16 + lr) * 384 + kwoff + t * 32 + lk);
    };
    auto MM = [&](bf16x8 (&a)[2], bf16x8 (&b)[3]) {
#pragma unroll
        for (int mt = 0; mt < 2; ++mt)
#pragma unroll
            for (int nt = 0; nt < 3; ++nt)
                acc[mt][nt] = __builtin_amdgcn_mfma_f32_16x16x32_bf16(a[mt], b[nt], acc[mt][nt], 0, 0, 0);
    };

    LD(0, a0, b0);
#pragma unroll
    for (int t = 0; t < 6; t += 2) {
        if (t + 1 < 6) LD(t + 1, a1, b1);
        MM(a0, b0);
        if (t + 2 < 6) LD(t + 2, a0, b0);
        if (t + 1 < 6) MM(a1, b1);
    }

    int crow = lkq * 4;
    if (kh == 1) {
#pragma unroll
        for (int mt = 0; mt < 2; ++mt)
#pragma unroll
            for (int r = 0; r < 4; ++r)
#pragma unroll
                for (int nt = 0; nt < 3; ++nt)
                    part[(mt * 16 + crow + r) * 192 + nb + nt * 16 + lr] = acc[mt][nt][r];
    }
    __syncthreads();
    if (kh == 0) {
#pragma unroll
        for (int mt = 0; mt < 2; ++mt)
#pragma unroll
            for (int r = 0; r < 4; ++r) {
                int orow = row0 + mt * 16 + crow + r;
#pragma unroll
                for (int nt = 0; nt < 3; ++nt) {
                    int nn = nb + nt * 16 + lr;
                    float s = acc[mt][nt][r] + part[(mt * 16 + crow + r) * 192 + nn] + bias[nn];
                    s = fmaxf(s, 0.f);
                    if (ACT) s = 0.5f * (bf2f(hprev[(size_t)orow * 192 + nn]) + s);
                    outp[(size_t)orow * 192 + nn] = f2bf(s);
                }
            }
    }
}

// ---------------------------------------------------------------------------
// final head: block = 64 rows x 4 subs; each sub handles 48 k; quad shfl reduce
// ---------------------------------------------------------------------------
__global__ void head_a2(const ushort* __restrict__ y, const float* __restrict__ Wg,
                        const float* __restrict__ loopWg, float* __restrict__ t)
{
    int tid = threadIdx.x;
    int rloc = tid >> 2, sub = tid & 3;
    int bm = blockIdx.x * 64 + rloc;
    if (bm >= MTOT) return;
    float s[6];
#pragma unroll
    for (int c = 0; c < 6; ++c) s[c] = 0.f;
#pragma unroll
    for (int kk = 0; kk < 6; ++kk) {
        int kg = sub * 6 + kk;
        bf16x8 v = *(const bf16x8*)(y + (size_t)bm * 192 + kg * 8);
#pragma unroll
        for (int e = 0; e < 8; ++e) {
            float f = bf2f((ushort)v[e]);
            int k = kg * 8 + e;
            s[0] += f * Wg[k * 3 + 0];
            s[1] += f * Wg[k * 3 + 1];
            s[2] += f * Wg[k * 3 + 2];
            s[3] += f * loopWg[k * 3 + 0];
            s[4] += f * loopWg[k * 3 + 1];
            s[5] += f * loopWg[k * 3 + 2];
        }
    }
#pragma unroll
    for (int o = 1; o <= 2; o <<= 1)
#pragma unroll
        for (int c = 0; c < 6; ++c) s[c] += __shfl_xor(s[c], o);
    if (sub == 0) {
#pragma unroll
        for (int c = 0; c < 6; ++c) t[(size_t)bm * 6 + c] = s[c];
    }
}

__global__ void head_b(const float* __restrict__ t, const int* __restrict__ cols,
                       const float* __restrict__ vals, const float* __restrict__ bg,
                       float* __restrict__ out)
{
    int idx = blockIdx.x * 256 + threadIdx.x;
    if (idx >= MTOT * 3) return;
    int bm = idx / 3, c = idx % 3;
    int b = bm / N3V, m = bm % N3V;
    float s = 0.f;
#pragma unroll
    for (int j = 0; j < 6; ++j)
        s += vals[m * 6 + j] * t[((size_t)b * N3V + cols[m * 6 + j]) * 6 + c];
    s += t[(size_t)bm * 6 + 3 + c] + bg[c];
    out[idx] = s;
}

// ---------------------------------------------------------------------------
extern "C" void kernel_launch(void* const* d_in, const int* in_sizes, int n_in,
                              void* d_out, int out_size, void* d_ws, size_t ws_size,
                              hipStream_t stream)
{
    const float* x        = (const float*)d_in[0];
    const float* x2       = (const float*)d_in[1];
    const float* xh       = (const float*)d_in[2];
    const float* Wq       = (const float*)d_in[3];
    const float* bq       = (const float*)d_in[4];
    const float* Wk       = (const float*)d_in[5];
    const float* bk       = (const float*)d_in[6];
    const float* Wv       = (const float*)d_in[7];
    const float* bv       = (const float*)d_in[8];
    const float* adj      = (const float*)d_in[9];
    const int*   unpool   = (const int*)d_in[10];
    const float* W_in     = (const float*)d_in[11];
    const float* loopW_in = (const float*)d_in[12];
    const float* b_in     = (const float*)d_in[13];
    const float* res_W    = (const float*)d_in[14];
    const float* res_loopW= (const float*)d_in[15];
    const float* res_b    = (const float*)d_in[16];
    const float* W_out    = (const float*)d_in[17];
    const float* loopW_out= (const float*)d_in[18];
    const float* b_out    = (const float*)d_in[19];
    const float* Wg       = (const float*)d_in[20];
    const float* loopWg   = (const float*)d_in[21];
    const float* bg       = (const float*)d_in[22];
    float* out = (float*)d_out;

    char* ws = (char*)d_ws;
    size_t o = 0;
    auto alloc = [&](size_t bytes) { char* p = ws + o; o += (bytes + 255) & ~(size_t)255; return p; };
    float*  q    = (float*)alloc((size_t)M2 * 8 * 4);
    float*  kbuf = (float*)alloc((size_t)M2 * 8 * 4);
    float*  vbuf = (float*)alloc((size_t)M2 * 8 * 4);
    float*  att  = (float*)alloc((size_t)M2 * 8 * 4);
    int*    cols = (int*)alloc((size_t)N3V * 6 * 4);
    float*  vals = (float*)alloc((size_t)N3V * 6 * 4);
    int*    eidx = (int*)alloc((size_t)N3V * 12 * 4);
    float*  ewgt = (float*)alloc((size_t)N3V * 12 * 4);
    int*    sidx = (int*)alloc((size_t)N3V * 2 * 4);
    ushort* F    = (ushort*)alloc((size_t)M2 * KPAD2 * 2);
    ushort* wt_e = (ushort*)alloc((size_t)384 * KPAD2 * 2);
    ushort* wt_r = (ushort*)alloc((size_t)13 * 192 * 384 * 2);
    ushort* u2   = (ushort*)alloc((size_t)M2 * 384 * 2);
    ushort* h    = (ushort*)alloc((size_t)MTOT * 192 * 2);
    ushort* h2   = (ushort*)alloc((size_t)MTOT * 192 * 2);
    ushort* y    = (ushort*)alloc((size_t)MTOT * 192 * 2);
    float*  ts   = (float*)alloc((size_t)MTOT * 6 * 4);
    if (ws_size < o) return;

    qkv_kernel<<<(M2 + 255) / 256, 256, 0, stream>>>(x2, Wq, bq, Wk, bk, Wv, bv, q, kbuf, vbuf);
    attn_kernel2<<<dim3(NB, 10), 256, 0, stream>>>(q, kbuf, vbuf, att);
    adj_prep<<<N3V, 256, 0, stream>>>(adj, unpool, cols, vals, eidx, ewgt, sidx);
    build_F<<<M2, 256, 0, stream>>>(x, xh, att, F);
    prep_wt_all<<<(WT_E_TOT + WT_R_TOT + 255) / 256, 256, 0, stream>>>(
        W_in, loopW_in, res_W, res_loopW, W_out, loopW_out, wt_e, wt_r);

    // entry: u2 = F @ [W_in | loopW_in]   (M=9888, K=1216, k-split x2)
    gemm_entry<<<dim3((M2 + 63) / 64, 2), 512, 0, stream>>>(F, wt_e, u2);
    combine_entry<<<(MTOT + 7) / 8, 192, 0, stream>>>(u2, eidx, ewgt, sidx, b_in, h);

    int gg = MTOT / 32;              // 1233
    ushort* cur = h;
    ushort* nxt = h2;
    for (int i = 0; i < 6; ++i) {
        const float* B0 = res_b + (size_t)(i * 2 + 0) * 192;
        const float* B1 = res_b + (size_t)(i * 2 + 1) * 192;
        const ushort* W0 = wt_r + (size_t)(i * 2 + 0) * 192 * 384;
        const ushort* W1 = wt_r + (size_t)(i * 2 + 1) * 192 * 384;
        gconv_fused<0><<<gg, 512, 0, stream>>>(cur, cols, vals, W0, B0, nullptr, y);
        gconv_fused<1><<<gg, 512, 0, stream>>>(y, cols, vals, W1, B1, cur, nxt);
        ushort* tmp = cur; cur = nxt; nxt = tmp;
    }

    // out conv (relu)
    gconv_fused<0><<<gg, 512, 0, stream>>>(cur, cols, vals,
        wt_r + (size_t)12 * 192 * 384, b_out, nullptr, y);

    head_a2<<<(MTOT + 63) / 64, 256, 0, stream>>>(y, Wg, loopWg, ts);
    head_b<<<(MTOT * 3 + 255) / 256, 256, 0, stream>>>(ts, cols, vals, bg, out);
}